// Round 8
// baseline (401.898 us; speedup 1.0000x reference)
//
#include <hip/hip_runtime.h>
#include <hip/hip_bf16.h>

// ---------------- constants ----------------
static constexpr int B_   = 8;
static constexpr int LQ_  = 1800;
static constexpr int D_   = 256;
static constexpr int H_   = 8;
static constexpr int DFF_ = 1024;
static constexpr int LIN_ = 19947;
static constexpr int MQ_  = B_ * LQ_;       // 14400
static constexpr int NELEM_ = MQ_ * D_;     // 3,686,400

#define CDIV(a, b) (((a) + (b) - 1) / (b))

typedef unsigned short u16;
typedef unsigned int   u32;
typedef unsigned long long u64;
typedef __attribute__((ext_vector_type(8))) __bf16 bf16x8;
typedef __attribute__((ext_vector_type(4))) float  f32x4;
typedef __attribute__((ext_vector_type(4))) u32    u32x4;

#if __has_builtin(__builtin_amdgcn_exp2f)
#define EXP2(x) __builtin_amdgcn_exp2f(x)
#else
#define EXP2(x) exp2f(x)
#endif

// ---------------- bf16 helpers (RNE via native cast -> v_cvt_pk_bf16_f32) ----
__device__ __forceinline__ u16 f2bf(float f) {
    union { __bf16 h; u16 u; } v; v.h = (__bf16)f; return v.u;
}
__device__ __forceinline__ float bf2f(u16 u) {
    union { u32 u; float f; } v; v.u = ((u32)u) << 16;
    return v.f;
}

__device__ __forceinline__ f32x4 mfma_bf16(bf16x8 a, bf16x8 b, f32x4 c) {
    return __builtin_amdgcn_mfma_f32_16x16x32_bf16(a, b, c, 0, 0, 0);
}

// async global->LDS, 16B per lane, LDS dest = wave-uniform base + lane*16
__device__ __forceinline__ void gload16(const void* g, void* l) {
    __builtin_amdgcn_global_load_lds(
        (const __attribute__((address_space(1))) void*)g,
        (__attribute__((address_space(3))) void*)l,
        16, 0, 0);
}

// counted vmcnt wait (compile-time N); "memory" clobber pins memory-op order
template <int N> __device__ __forceinline__ void waitvm() {
    if constexpr (N == 0) asm volatile("s_waitcnt vmcnt(0)" ::: "memory");
    else if constexpr (N == 3) asm volatile("s_waitcnt vmcnt(3)" ::: "memory");
    else if constexpr (N == 4) asm volatile("s_waitcnt vmcnt(4)" ::: "memory");
    else if constexpr (N == 5) asm volatile("s_waitcnt vmcnt(5)" ::: "memory");
    else if constexpr (N == 6) asm volatile("s_waitcnt vmcnt(6)" ::: "memory");
}

// ---------------- small elementwise kernels ----------------
__global__ void k_quant(const float* __restrict__ w, const float* __restrict__ alpha,
                        u16* __restrict__ o, int n) {
    int i = blockIdx.x * blockDim.x + threadIdx.x;
    if (i >= n) return;
    float a = alpha[0];
    float wn = fminf(fmaxf(w[i] / a, -8.f), 7.f);
    o[i] = f2bf(rintf(wn) * a);
}

__global__ void k_cvt(const float* __restrict__ w, u16* __restrict__ o, int n) {
    int i = blockIdx.x * blockDim.x + threadIdx.x;
    if (i < n) o[i] = f2bf(w[i]);
}

__global__ void k_addcvt(const float* __restrict__ a, const float* __restrict__ b,
                         u16* __restrict__ o, int n) {
    int i = blockIdx.x * blockDim.x + threadIdx.x;
    if (i < n) o[i] = f2bf(a[i] + b[i]);
}

__global__ void k_addcvt2(const u16* __restrict__ a, const float* __restrict__ b,
                          u16* __restrict__ o, int n) {
    int i = blockIdx.x * blockDim.x + threadIdx.x;
    if (i < n) o[i] = f2bf(bf2f(a[i]) + b[i]);
}

// ---------------- staging-load helpers (k_gemm v1 only) ----------------
struct rawf8 { float4 a, b; };
__device__ __forceinline__ bf16x8 loadraw(const u16* p) { return *(const bf16x8*)p; }
__device__ __forceinline__ rawf8  loadraw(const float* p) {
    rawf8 r; r.a = *(const float4*)p; r.b = *(const float4*)(p + 4); return r;
}
__device__ __forceinline__ void wlds(u16* d, bf16x8 v) { *(bf16x8*)d = v; }
__device__ __forceinline__ void wlds(u16* d, rawf8 v) {
    bf16x8 r;
    r[0] = (__bf16)v.a.x; r[1] = (__bf16)v.a.y; r[2] = (__bf16)v.a.z; r[3] = (__bf16)v.a.w;
    r[4] = (__bf16)v.b.x; r[5] = (__bf16)v.b.y; r[6] = (__bf16)v.b.z; r[7] = (__bf16)v.b.w;
    *(bf16x8*)d = r;
}
__device__ __forceinline__ void storey(float* p, float v) { *p = v; }
__device__ __forceinline__ void storey(u16* p, float v)   { *p = f2bf(v); }

// ---------------- GEMM v3: Y = X @ W^T + bias ----------------------------
// 64xBN tile, 256 thr = 4 waves (2x2), wave tile 32x(BN/2).
// global_load_lds width-16 staging into LINEAR LDS (XOR slot swizzle on the
// per-lane GLOBAL source + matching swizzled ds_read). T4 counted-vmcnt
// pipeline: next tile's loads stay in flight across the barriers; vmcnt(L)
// waits only for the PREVIOUS tile. Two barriers per K-step, never vmcnt(0)
// mid-loop.
template <typename XT, typename OT, bool RELU, int BN>
__global__ __launch_bounds__(256) void k_gemm3(
    const XT* __restrict__ X, const u16* __restrict__ W,
    const float* __restrict__ bias, OT* __restrict__ Y,
    int M, int N, int K)
{
    constexpr int WN  = BN / 2;          // wave col span
    constexpr int NFR = WN / 16;         // B frags per wave
    constexpr bool XF32 = (sizeof(XT) == 4);
    constexpr int L = (XF32 ? 2 : 1) + BN / 64;     // gload_lds per thread per stage
    constexpr int ASZ = 64 * 32 * (XF32 ? 2 : 1);   // u16 units
    constexpr int BSZ = BN * 32;
    __shared__ __align__(16) u16 As[2][ASZ];
    __shared__ __align__(16) u16 Bs[2][BSZ];

    const int tid = threadIdx.x;
    const int wave = tid >> 6, lane = tid & 63;
    const int wr = wave >> 1, wc = wave & 1;
    const int fr = lane & 15, fg = lane >> 4;
    const int bm = blockIdx.x * 64, bn = blockIdx.y * BN;

    f32x4 acc[2][NFR];
    #pragma unroll
    for (int m = 0; m < 2; ++m)
        #pragma unroll
        for (int n = 0; n < NFR; ++n) acc[m][n] = (f32x4){0.f, 0.f, 0.f, 0.f};

    auto stageA = [&](int buf, int kt) {
        if constexpr (!XF32) {
            int r = (wave << 4) + (lane >> 2);
            int grow = bm + r; if (grow > M - 1) grow = M - 1;
            int cs = (lane & 3) ^ ((lane >> 3) & 3);        // slot ^ ((r>>1)&3)
            gload16((const u16*)X + (size_t)grow * K + (kt << 5) + (cs << 3),
                    &As[buf][wave * 512]);
        } else {
            float* Af = (float*)As[buf];
            #pragma unroll
            for (int t = 0; t < 2; ++t) {
                int r = (t << 5) + (wave << 3) + (lane >> 3);
                int grow = bm + r; if (grow > M - 1) grow = M - 1;
                int cs = (lane & 7) ^ ((lane >> 3) & 7);    // slot ^ (r&7)
                gload16((const float*)X + (size_t)grow * K + (kt << 5) + (cs << 2),
                        &Af[((t << 5) + (wave << 3)) * 32]);
            }
        }
    };
    auto stageB = [&](int buf, int kt) {
        #pragma unroll
        for (int t = 0; t < BN / 64; ++t) {
            int r = (t << 6) + (wave << 4) + (lane >> 2);
            int cs = (lane & 3) ^ ((lane >> 3) & 3);
            gload16(W + (size_t)(bn + r) * K + (kt << 5) + (cs << 3),
                    &Bs[buf][((t << 6) + (wave << 4)) * 32]);
        }
    };

    stageA(0, 0); stageB(0, 0);      // L loads in flight; first wait handles them

    const int nk = K >> 5;
    int cur = 0;
    for (int kt = 0; kt < nk; ++kt) {
        if (kt + 1 < nk) {
            stageA(cur ^ 1, kt + 1); stageB(cur ^ 1, kt + 1);   // 2L in flight
            waitvm<L>();             // previous tile landed; next stays in flight
        } else {
            waitvm<0>();
        }
        __builtin_amdgcn_s_barrier();    // tile kt visible to all waves

        bf16x8 af[2], bg[NFR];
        #pragma unroll
        for (int m = 0; m < 2; ++m) {
            int r = wr * 32 + m * 16 + fr;
            if constexpr (!XF32) {
                af[m] = *(const bf16x8*)&As[cur][r * 32 + ((fg ^ ((fr >> 1) & 3)) << 3)];
            } else {
                const float* Af = (const float*)As[cur];
                int s0 = (fg << 1) ^ (fr & 7);
                f32x4 x0 = *(const f32x4*)&Af[r * 32 + (s0 << 2)];
                f32x4 x1 = *(const f32x4*)&Af[r * 32 + ((s0 ^ 1) << 2)];
                #pragma unroll
                for (int j = 0; j < 4; ++j) {
                    af[m][j]     = (__bf16)x0[j];
                    af[m][4 + j] = (__bf16)x1[j];
                }
            }
        }
        #pragma unroll
        for (int n = 0; n < NFR; ++n) {
            int r = wc * WN + n * 16 + fr;
            bg[n] = *(const bf16x8*)&Bs[cur][r * 32 + ((fg ^ ((fr >> 1) & 3)) << 3)];
        }
        #pragma unroll
        for (int m = 0; m < 2; ++m)
            #pragma unroll
            for (int n = 0; n < NFR; ++n)
                acc[m][n] = mfma_bf16(af[m], bg[n], acc[m][n]);

        __builtin_amdgcn_s_barrier();    // all waves done reading buf cur
        cur ^= 1;
    }

    #pragma unroll
    for (int m = 0; m < 2; ++m) {
        #pragma unroll
        for (int i = 0; i < 4; ++i) {
            int grow = bm + wr * 32 + m * 16 + fg * 4 + i;
            if (grow >= M) continue;
            #pragma unroll
            for (int n = 0; n < NFR; ++n) {
                int gcol = bn + wc * WN + n * 16 + fr;
                float v = acc[m][n][i] + bias[gcol];
                if (RELU) v = fmaxf(v, 0.f);
                storey(Y + (size_t)grow * N + gcol, v);
            }
        }
    }
}

// ---------------- GEMM v1 (kept for N=128 aw projection) ----------------
template <typename XT, typename OT, bool RELU>
__global__ __launch_bounds__(256) void k_gemm(
    const XT* __restrict__ X, const u16* __restrict__ W,
    const float* __restrict__ bias, OT* __restrict__ Y,
    int M, int N, int K)
{
    __shared__ u16 Ash[128 * 40];
    __shared__ u16 Bsh[128 * 40];
    const int tid = threadIdx.x;
    const int wave = tid >> 6, lane = tid & 63;
    const int wr = wave >> 1, wc = wave & 1;
    const int fr = lane & 15, fg = lane >> 4;
    const int bm = blockIdx.x * 128, bn = blockIdx.y * 128;
    const int srow = tid >> 2, sc = (tid & 3) * 8;

    f32x4 acc[4][4];
    #pragma unroll
    for (int m = 0; m < 4; ++m)
        #pragma unroll
        for (int n = 0; n < 4; ++n) acc[m][n] = (f32x4){0.f, 0.f, 0.f, 0.f};

    for (int k0 = 0; k0 < K; k0 += 32) {
        __syncthreads();
        #pragma unroll
        for (int i = 0; i < 2; ++i) {
            int row = srow + i * 64;
            int gr = bm + row; if (gr > M - 1) gr = M - 1;
            wlds(&Ash[row * 40 + sc], loadraw(X + (size_t)gr * K + k0 + sc));
            int wn = bn + row; if (wn > N - 1) wn = N - 1;
            wlds(&Bsh[row * 40 + sc], loadraw(W + (size_t)wn * K + k0 + sc));
        }
        __syncthreads();
        bf16x8 af[4], bg[4];
        #pragma unroll
        for (int m = 0; m < 4; ++m)
            af[m] = *(const bf16x8*)&Ash[(wr * 64 + m * 16 + fr) * 40 + fg * 8];
        #pragma unroll
        for (int n = 0; n < 4; ++n)
            bg[n] = *(const bf16x8*)&Bsh[(wc * 64 + n * 16 + fr) * 40 + fg * 8];
        #pragma unroll
        for (int m = 0; m < 4; ++m)
            #pragma unroll
            for (int n = 0; n < 4; ++n)
                acc[m][n] = mfma_bf16(af[m], bg[n], acc[m][n]);
    }

    #pragma unroll
    for (int m = 0; m < 4; ++m) {
        #pragma unroll
        for (int i = 0; i < 4; ++i) {
            int grow = bm + wr * 64 + m * 16 + fg * 4 + i;
            if (grow >= M) continue;
            #pragma unroll
            for (int n = 0; n < 4; ++n) {
                int gcol = bn + wc * 64 + n * 16 + fr;
                if (gcol >= N) continue;
                float v = acc[m][n][i] + bias[gcol];
                if (RELU) v = fmaxf(v, 0.f);
                storey(Y + (size_t)grow * N + gcol, v);
            }
        }
    }
}

// ---------------- flash self-attention v3 (MFMA bf16, KVBLK=128) ----------------
__global__ __launch_bounds__(256) void k_attn(
    const u16* __restrict__ Q, const u16* __restrict__ K,
    const u16* __restrict__ V, u16* __restrict__ O)
{
    __shared__ u16 Ks[128 * 40];       // [key][dh], stride 40
    __shared__ u16 Vt[32 * 136];       // [dh][kv-slot], stride 136 (slot = permuted kv)
    const int b = blockIdx.z, h = blockIdx.y;
    const int q0 = blockIdx.x * 64;
    const int tid = threadIdx.x;
    const int wave = tid >> 6, lane = tid & 63;
    const int fr = lane & 15, fg = lane >> 4;
    constexpr float C2 = 0.25503486f;   // log2(e)/sqrt(32), folded into Q

    int qg = q0 + wave * 16 + fr; if (qg >= LQ_) qg = LQ_ - 1;
    bf16x8 qf;
    {
        bf16x8 qraw = *(const bf16x8*)&Q[((size_t)(b * LQ_ + qg)) * 256 + h * 32 + fg * 8];
        #pragma unroll
        for (int j = 0; j < 8; ++j) qf[j] = (__bf16)((float)qraw[j] * C2);
    }

    const bf16x8 ones = {(__bf16)1.f, (__bf16)1.f, (__bf16)1.f, (__bf16)1.f,
                         (__bf16)1.f, (__bf16)1.f, (__bf16)1.f, (__bf16)1.f};

    f32x4 o0 = (f32x4){0.f,0.f,0.f,0.f}, o1 = (f32x4){0.f,0.f,0.f,0.f};
    f32x4 lacc = (f32x4){0.f,0.f,0.f,0.f};

    const int kr = tid >> 1, kc = (tid & 1) * 16;   // K staging: row, col16
    const int vp = lane, vdh = wave * 8;            // V staging: kv-pair, dh block
    const int cp = ((vp >> 4) << 4) | (((vp >> 1) & 3) << 2) | (((vp >> 3) & 1) << 1) | (vp & 1);

    for (int kb0 = 0; kb0 < LQ_; kb0 += 128) {
        const bool tail = (kb0 + 128 > LQ_);
        __syncthreads();
        {
            int kg = kb0 + kr; if (kg >= LQ_) kg = LQ_ - 1;
            const u16* kp = &K[((size_t)(b * LQ_ + kg)) * 256 + h * 32 + kc];
            *(bf16x8*)&Ks[kr * 40 + kc]     = *(const bf16x8*)kp;
            *(bf16x8*)&Ks[kr * 40 + kc + 8] = *(const bf16x8*)(kp + 8);
            int v0 = kb0 + 2 * vp, v1 = v0 + 1;
            if (v0 >= LQ_) v0 = LQ_ - 1;
            if (v1 >= LQ_) v1 = LQ_ - 1;
            union { bf16x8 v; u16 s[8]; } va, vb2;
            va.v  = *(const bf16x8*)&V[((size_t)(b * LQ_ + v0)) * 256 + h * 32 + vdh];
            vb2.v = *(const bf16x8*)&V[((size_t)(b * LQ_ + v1)) * 256 + h * 32 + vdh];
            #pragma unroll
            for (int j = 0; j < 8; ++j)
                *(u32*)&Vt[(vdh + j) * 136 + 2 * cp] = (u32)va.s[j] | ((u32)vb2.s[j] << 16);
        }
        __syncthreads();

        u32x4 pq[4];
        #pragma unroll
        for (int f = 0; f < 8; ++f) {
            bf16x8 ka = *(const bf16x8*)&Ks[(f * 16 + fr) * 40 + fg * 8];
            f32x4 s = mfma_bf16(ka, qf, (f32x4){0.f,0.f,0.f,0.f});
            if (tail) {
                #pragma unroll
                for (int i = 0; i < 4; ++i)
                    if (kb0 + f * 16 + fg * 4 + i >= LQ_) s[i] = -3e38f;
            }
            float p0 = EXP2(s[0]), p1 = EXP2(s[1]);
            float p2 = EXP2(s[2]), p3 = EXP2(s[3]);
            union { __bf16 h[2]; u32 w; } c0, c1;
            c0.h[0] = (__bf16)p0; c0.h[1] = (__bf16)p1;
            c1.h[0] = (__bf16)p2; c1.h[1] = (__bf16)p3;
            pq[f >> 1][(f & 1) * 2 + 0] = c0.w;
            pq[f >> 1][(f & 1) * 2 + 1] = c1.w;
        }

        #pragma unroll
        for (int ks = 0; ks < 4; ++ks) {
            bf16x8 pb  = __builtin_bit_cast(bf16x8, pq[ks]);
            bf16x8 va0 = *(const bf16x8*)&Vt[fr * 136 + ks * 32 + fg * 8];
            bf16x8 va1 = *(const bf16x8*)&Vt[(16 + fr) * 136 + ks * 32 + fg * 8];
            o0 = mfma_bf16(va0, pb, o0);
            o1 = mfma_bf16(va1, pb, o1);
            lacc = mfma_bf16(ones, pb, lacc);
        }
    }

    float inv = 1.f / lacc[0];
    int qout = q0 + wave * 16 + fr;
    if (qout < LQ_) {
        size_t base = ((size_t)(b * LQ_ + qout)) * 256 + h * 32;
        #pragma unroll
        for (int i = 0; i < 4; ++i) {
            O[base + fg * 4 + i]      = f2bf(o0[i] * inv);
            O[base + 16 + fg * 4 + i] = f2bf(o1[i] * inv);
        }
    }
}

// ---------------- residual + LayerNorm ----------------
__device__ __forceinline__ float ldf(const float* p) { return *p; }
__device__ __forceinline__ float ldf(const u16* p)   { return bf2f(*p); }

template <typename RT, typename OT>
__global__ __launch_bounds__(256) void k_resln(
    const u16* __restrict__ X, const RT* __restrict__ R,
    const float* __restrict__ g, const float* __restrict__ bb,
    OT* __restrict__ O)
{
    const int row = blockIdx.x;
    const int d = threadIdx.x;
    const size_t off = (size_t)row * D_ + d;
    float v = ldf(R + off) + bf2f(X[off]);
    __shared__ float r1[4], r2[4];
    int lane = d & 63, wid = d >> 6;
    float s = v;
    #pragma unroll
    for (int o_ = 32; o_ >= 1; o_ >>= 1) s += __shfl_xor(s, o_);
    if (lane == 0) r1[wid] = s;
    __syncthreads();
    float mean = (r1[0] + r1[1] + r1[2] + r1[3]) * (1.f / 256.f);
    float dv = v - mean;
    float sq = dv * dv;
    #pragma unroll
    for (int o_ = 32; o_ >= 1; o_ >>= 1) sq += __shfl_xor(sq, o_);
    if (lane == 0) r2[wid] = sq;
    __syncthreads();
    float var = (r2[0] + r2[1] + r2[2] + r2[3]) * (1.f / 256.f);
    storey(O + off, dv / sqrtf(var + 1e-5f) * g[d] + bb[d]);
}

// ---------------- deformable sampling (two-phase, LDS precompute) ----------------
__global__ __launch_bounds__(256) void k_sample(
    const float* __restrict__ offs, const float* __restrict__ aw,
    const u16* __restrict__ value, const float* __restrict__ refp,
    u16* __restrict__ acc_out)
{
    __shared__ u32 pts[2][128][8];   // [qsub][lp*8+h][0..3 off, 4..7 w]
    const int t = threadIdx.x;
    const int bq0 = blockIdx.x * 2;          // 2 queries, same batch (LQ even)
    const int b = bq0 / LQ_;

    constexpr int Hl[4] = {100, 50, 25, 13};
    constexpr int Wl[4] = {150, 75, 38, 19};
    constexpr int LS[4] = {0, 15000, 18750, 19700};

    // ---- phase 1 ----
    {
        const int qsub = t >> 7;
        const int pt = t & 127;
        const int h = pt >> 4, lp = pt & 15;
        const int l = lp >> 2, p = lp & 3;
        const int bq = bq0 + qsub;

        float2 oxy = *(const float2*)&offs[(size_t)bq * 256 + h * 32 + l * 8 + p * 2];
        float av = aw[(size_t)bq * 128 + h * 16 + lp];
        float mx = av;
        #pragma unroll
        for (int s = 1; s < 16; s <<= 1) mx = fmaxf(mx, __shfl_xor(mx, s));
        float e = __expf(av - mx);
        float sum = e;
        #pragma unroll
        for (int s = 1; s < 16; s <<= 1) sum += __shfl_xor(sum, s);
        float a = e / sum;

        float2 rxy = *(const float2*)&refp[(size_t)bq * 8 + l * 2];
        const float Wf = (float)Wl[l], Hf = (float)Hl[l];
        float x = (rxy.x + oxy.x / Wf) * Wf - 0.5f;
        float y = (rxy.y + oxy.y / Hf) * Hf - 0.5f;
        float x0f = floorf(x), y0f = floorf(y);
        int x0 = (int)x0f, y0 = (int)y0f;
        float wx1 = x - x0f, wy1 = y - y0f;
        float wx0 = 1.f - wx1, wy0 = 1.f - wy1;

        u32 ov[4]; float wv[4];
        #pragma unroll
        for (int c = 0; c < 4; ++c) {
            int cy = c >> 1, cx = c & 1;
            int yi = y0 + cy, xi = x0 + cx;
            bool valid = (yi >= 0) && (yi < Hl[l]) && (xi >= 0) && (xi < Wl[l]);
            ov[c] = valid ? (u32)((LS[l] + yi * Wl[l] + xi) * 256 + h * 32) : 0u;
            float w = (cy ? wy1 : wy0) * (cx ? wx1 : wx0) * a;
            wv[c] = valid ? w : 0.f;
        }
        u32* dst = pts[qsub][lp * 8 + h];
        *(uint4*)dst = make_uint4(ov[0], ov[1], ov[2], ov[3]);
        float4 wq = make_float4(wv[0], wv[1], wv[2], wv[3]);
        *(float4*)(dst + 4) = wq;
    }
    __syncthreads();

    // ---- phase 2 ----
    const int qsub = t >> 7;
    const int h = (t >> 4) & 7;
    const int dp = t & 15;                    // dh pair: dh = 2*dp, 2*dp+1
    const u16* vb = value + (size_t)b * LIN_ * 256 + 2 * dp;
    float a0 = 0.f, a1 = 0.f;
    #pragma unroll
    for (int i = 0; i < 16; ++i) {
        const u32* P = pts[qsub][i * 8 + h];
        uint4 o4 = *(const uint4*)P;
        float4 w4 = *(const float4*)(P + 4);
        u32 g;
        g = *(const u32*)&vb[o4.x]; a0 += w4.x * bf2f((u16)g); a1 += w4.x * bf2f((u16)(g >> 16));
        g = *(const u32*)&vb[o4.y]; a0 += w4.y * bf2f((u16)g); a1 += w4.y * bf2f((u16)(g >> 16));
        g = *(const u32*)&vb[o4.z]; a0 += w4.z * bf2f((u16)g); a1 += w4.z * bf2f((u16)(g >> 16));
        g = *(const u32*)&vb[o4.w]; a0 += w4.w * bf2f((u16)g); a1 += w4.w * bf2f((u16)(g >> 16));
    }
    const int bq = bq0 + qsub;
    u32 packed = (u32)f2bf(a0) | ((u32)f2bf(a1) << 16);
    *(u32*)&acc_out[(size_t)bq * 256 + h * 32 + 2 * dp] = packed;
}

// ---------------- launch ----------------
extern "C" void kernel_launch(void* const* d_in, const int* in_sizes, int n_in,
                              void* d_out, int out_size, void* d_ws, size_t ws_size,
                              hipStream_t stream)
{
    (void)in_sizes; (void)n_in; (void)out_size; (void)ws_size;
    const float* tgt   = (const float*)d_in[0];
    const float* qpos  = (const float*)d_in[1];
    const float* refp  = (const float*)d_in[2];
    const float* src   = (const float*)d_in[3];
    const float* qW    = (const float*)d_in[4];
    const float* qb    = (const float*)d_in[5];
    const float* kW    = (const float*)d_in[6];
    const float* kb    = (const float*)d_in[7];
    const float* vW    = (const float*)d_in[8];
    const float* vb    = (const float*)d_in[9];
    const float* oW    = (const float*)d_in[10];
    const float* ob    = (const float*)d_in[11];
    const float* a_q   = (const float*)d_in[12];
    const float* a_k   = (const float*)d_in[13];
    const float* a_v   = (const float*)d_in[14];
    const float* a_o   = (const float*)d_in[15];
    const float* val_W = (const float*)d_in[16];
    const float* val_b = (const float*)d_in[17];
    const float* a_val = (const float*)d_in[18];
    const float* off_W = (const float*)d_in[19];
    const float* off_b = (const float*)d_in[20];
    const float* aw_W  = (const float*)d_in[21];
    const float* aw_b  = (const float*)d_in[22];
    const float* out_W = (const float*)d_in[23];
    const float* out_b = (const float*)d_in[24];
    const float* a_out = (const float*)d_in[25];
    const float* W1    = (const float*)d_in[26];
    const float* b1    = (const float*)d_in[27];
    const float* a_w1  = (const float*)d_in[28];
    const float* W2    = (const float*)d_in[29];
    const float* b2    = (const float*)d_in[30];
    const float* a_w2  = (const float*)d_in[31];
    const float* ln1_g = (const float*)d_in[32];
    const float* ln1_b = (const float*)d_in[33];
    const float* ln2_g = (const float*)d_in[34];
    const float* ln2_b = (const float*)d_in[35];
    const float* ln3_g = (const float*)d_in[36];
    const float* ln3_b = (const float*)d_in[37];

    // ---- workspace layout ----
    u16* wq_q  = (u16*)d_ws;
    u16* wq_k  = wq_q + 65536;
    u16* wq_v  = wq_k + 65536;
    u16* wq_o  = wq_v + 65536;
    u16* wq_vl = wq_o + 65536;
    u16* wq_ot = wq_vl + 65536;
    u16* w_off = wq_ot + 65536;
    u16* w_aw  = w_off + 65536;
    u16* wq_1  = w_aw + 32768;
    u16* wq_2  = wq_1 + 262144;
    u16* bufA  = wq_2 + 262144;      // NELEM bf16 each
    u16* bufB  = bufA + NELEM_;
    u16* bufC  = bufB + NELEM_;
    u16* bufD  = bufC + NELEM_;
    u16* bufE  = bufD + NELEM_;
    float* offs = (float*)(bufE + NELEM_);   // NELEM f32
    float* awb  = offs + NELEM_;             // MQ*128 f32
    u16* valb   = (u16*)(awb + MQ_ * 128);   // B*LIN*256 bf16 (later reused as ffn1)

    const int TB = 256;
    const int MVAL = B_ * LIN_;
    const int GM = MQ_ / 64;                 // 225 (exact)
    const int GV = CDIV(MVAL, 64);           // 2494

    // weights
    k_quant<<<CDIV(65536, TB), TB, 0, stream>>>(qW, a_q, wq_q, 65536);
    k_quant<<<CDIV(65536, TB), TB, 0, stream>>>(kW, a_k, wq_k, 65536);
    k_quant<<<CDIV(65536, TB), TB, 0, stream>>>(vW, a_v, wq_v, 65536);
    k_quant<<<CDIV(65536, TB), TB, 0, stream>>>(oW, a_o, wq_o, 65536);
    k_quant<<<CDIV(65536, TB), TB, 0, stream>>>(val_W, a_val, wq_vl, 65536);
    k_quant<<<CDIV(65536, TB), TB, 0, stream>>>(out_W, a_out, wq_ot, 65536);
    k_quant<<<CDIV(262144, TB), TB, 0, stream>>>(W1, a_w1, wq_1, 262144);
    k_quant<<<CDIV(262144, TB), TB, 0, stream>>>(W2, a_w2, wq_2, 262144);
    k_cvt<<<CDIV(65536, TB), TB, 0, stream>>>(off_W, w_off, 65536);
    k_cvt<<<CDIV(32768, TB), TB, 0, stream>>>(aw_W, w_aw, 32768);

    // activation prep
    k_addcvt<<<CDIV(NELEM_, TB), TB, 0, stream>>>(tgt, qpos, bufA, NELEM_);  // qk_in
    k_cvt<<<CDIV(NELEM_, TB), TB, 0, stream>>>(tgt, bufB, NELEM_);           // tgt_bf

    // ---- self-attention ----
    k_gemm3<u16, u16, false, 128><<<dim3(GM, 2), TB, 0, stream>>>(bufA, wq_q, qb, bufC, MQ_, 256, 256);
    k_gemm3<u16, u16, false, 128><<<dim3(GM, 2), TB, 0, stream>>>(bufA, wq_k, kb, bufD, MQ_, 256, 256);
    k_gemm3<u16, u16, false, 128><<<dim3(GM, 2), TB, 0, stream>>>(bufB, wq_v, vb, bufE, MQ_, 256, 256);
    k_attn<<<dim3(CDIV(LQ_,64), H_, B_), TB, 0, stream>>>(bufC, bufD, bufE, bufA);       // sa -> A
    k_gemm3<u16, u16, false, 128><<<dim3(GM, 2), TB, 0, stream>>>(bufA, wq_o, ob, bufB, MQ_, 256, 256);
    k_resln<float, u16><<<MQ_, TB, 0, stream>>>(bufB, tgt, ln2_g, ln2_b, bufC);          // tgt2 -> C

    // ---- deformable cross-attention ----
    k_addcvt2<<<CDIV(NELEM_, TB), TB, 0, stream>>>(bufC, qpos, bufD, NELEM_);            // query -> D
    k_gemm3<float, u16, false, 128><<<dim3(GV, 2), TB, 0, stream>>>(src, wq_vl, val_b, valb, MVAL, 256, 256);
    k_gemm3<u16, float, false, 128><<<dim3(GM, 2), TB, 0, stream>>>(bufD, w_off, off_b, offs, MQ_, 256, 256);
    k_gemm<u16, float, false><<<dim3(CDIV(MQ_,128), 1), TB, 0, stream>>>(bufD, w_aw, aw_b, awb, MQ_, 128, 256);
    k_sample<<<MQ_ / 2, TB, 0, stream>>>(offs, awb, valb, refp, bufE);                   // acc -> E
    k_gemm3<u16, u16, false, 128><<<dim3(GM, 2), TB, 0, stream>>>(bufE, wq_ot, out_b, bufA, MQ_, 256, 256);
    k_resln<u16, u16><<<MQ_, TB, 0, stream>>>(bufA, bufC, ln1_g, ln1_b, bufB);           // tgt3 -> B

    // ---- FFN ----
    u16* ffn1 = valb;  // value dead after k_sample
    k_gemm3<u16, u16, true , 128><<<dim3(GM, 8), TB, 0, stream>>>(bufB, wq_1, b1, ffn1, MQ_, 1024, 256);
    k_gemm3<u16, u16, false, 128><<<dim3(GM, 2), TB, 0, stream>>>(ffn1, wq_2, b2, bufD, MQ_, 256, 1024);
    k_resln<u16, float><<<MQ_, TB, 0, stream>>>(bufD, bufB, ln3_g, ln3_b, (float*)d_out);
}

// Round 9
// 340.276 us; speedup vs baseline: 1.1811x; 1.1811x over previous
//
#include <hip/hip_runtime.h>
#include <hip/hip_bf16.h>

// ---------------- constants ----------------
static constexpr int B_   = 8;
static constexpr int LQ_  = 1800;
static constexpr int D_   = 256;
static constexpr int H_   = 8;
static constexpr int DFF_ = 1024;
static constexpr int LIN_ = 19947;
static constexpr int MQ_  = B_ * LQ_;       // 14400
static constexpr int NELEM_ = MQ_ * D_;     // 3,686,400

#define CDIV(a, b) (((a) + (b) - 1) / (b))

typedef unsigned short u16;
typedef unsigned int   u32;
typedef unsigned long long u64;
typedef __attribute__((ext_vector_type(8))) __bf16 bf16x8;
typedef __attribute__((ext_vector_type(4))) float  f32x4;
typedef __attribute__((ext_vector_type(4))) u32    u32x4;

#if __has_builtin(__builtin_amdgcn_exp2f)
#define EXP2(x) __builtin_amdgcn_exp2f(x)
#else
#define EXP2(x) exp2f(x)
#endif

// ---------------- bf16 helpers ----------------
__device__ __forceinline__ u16 f2bf(float f) {
    union { __bf16 h; u16 u; } v; v.h = (__bf16)f; return v.u;
}
__device__ __forceinline__ float bf2f(u16 u) {
    union { u32 u; float f; } v; v.u = ((u32)u) << 16;
    return v.f;
}

__device__ __forceinline__ f32x4 mfma_bf16(bf16x8 a, bf16x8 b, f32x4 c) {
    return __builtin_amdgcn_mfma_f32_16x16x32_bf16(a, b, c, 0, 0, 0);
}

// async global->LDS, 16B per lane, LDS dest = wave-uniform base + lane*16
__device__ __forceinline__ void gload16(const void* g, void* l) {
    __builtin_amdgcn_global_load_lds(
        (const __attribute__((address_space(1))) void*)g,
        (__attribute__((address_space(3))) void*)l,
        16, 0, 0);
}

// counted vmcnt wait (compile-time N); "memory" clobber pins memory-op order
template <int N> __device__ __forceinline__ void waitvm() {
    if constexpr (N == 0) asm volatile("s_waitcnt vmcnt(0)" ::: "memory");
    else if constexpr (N == 3) asm volatile("s_waitcnt vmcnt(3)" ::: "memory");
    else if constexpr (N == 4) asm volatile("s_waitcnt vmcnt(4)" ::: "memory");
    else if constexpr (N == 5) asm volatile("s_waitcnt vmcnt(5)" ::: "memory");
    else if constexpr (N == 6) asm volatile("s_waitcnt vmcnt(6)" ::: "memory");
}

// ---------------- one-shot weight prep (all quant/cvt/bias fusion) --------
// wout layout (u16): qW kW vW oW valW outW | W1 W2 | offW awW   (1,015,808)
// bout layout (f32): qkb[512] | oawb[384]
__global__ void k_prep(
    const float* __restrict__ qW,   const float* __restrict__ kW,
    const float* __restrict__ vW,   const float* __restrict__ oW,
    const float* __restrict__ valW, const float* __restrict__ outW,
    const float* __restrict__ W1,   const float* __restrict__ W2,
    const float* __restrict__ offW, const float* __restrict__ awW,
    const float* __restrict__ a_q,  const float* __restrict__ a_k,
    const float* __restrict__ a_v,  const float* __restrict__ a_o,
    const float* __restrict__ a_val,const float* __restrict__ a_out,
    const float* __restrict__ a_w1, const float* __restrict__ a_w2,
    const float* __restrict__ qb,   const float* __restrict__ kb,
    const float* __restrict__ off_b,const float* __restrict__ aw_b,
    u16* __restrict__ wout, float* __restrict__ bout)
{
    int i = blockIdx.x * 256 + threadIdx.x;
    auto q8 = [&](const float* w, const float* al, int off) {
        float a = al[0];
        float wn = fminf(fmaxf(w[off] / a, -8.f), 7.f);
        wout[i] = f2bf(rintf(wn) * a);
    };
    if      (i <   65536) q8(qW,   a_q,   i);
    else if (i <  131072) q8(kW,   a_k,   i -   65536);
    else if (i <  196608) q8(vW,   a_v,   i -  131072);
    else if (i <  262144) q8(oW,   a_o,   i -  196608);
    else if (i <  327680) q8(valW, a_val, i -  262144);
    else if (i <  393216) q8(outW, a_out, i -  327680);
    else if (i <  655360) q8(W1,   a_w1,  i -  393216);
    else if (i <  917504) q8(W2,   a_w2,  i -  655360);
    else if (i <  983040) wout[i] = f2bf(offW[i - 917504]);
    else if (i < 1015808) wout[i] = f2bf(awW[i - 983040]);
    else if (i < 1016320) { int j = i - 1015808; bout[j]       = (j < 256) ? qb[j]    : kb[j - 256];  }
    else if (i < 1016704) { int j = i - 1016320; bout[512 + j] = (j < 256) ? off_b[j] : aw_b[j - 256]; }
}

// tgt prep: bufA = bf16(tgt + qpos), bufB = bf16(tgt)
__global__ void k_tgtprep(const float* __restrict__ tgt, const float* __restrict__ qpos,
                          u16* __restrict__ A, u16* __restrict__ Bb, int n) {
    int i = blockIdx.x * blockDim.x + threadIdx.x;
    if (i < n) { float t = tgt[i]; A[i] = f2bf(t + qpos[i]); Bb[i] = f2bf(t); }
}

__global__ void k_addcvt2(const u16* __restrict__ a, const float* __restrict__ b,
                          u16* __restrict__ o, int n) {
    int i = blockIdx.x * blockDim.x + threadIdx.x;
    if (i < n) o[i] = f2bf(bf2f(a[i]) + b[i]);
}

__device__ __forceinline__ void storey(float* p, float v) { *p = v; }
__device__ __forceinline__ void storey(u16* p, float v)   { *p = f2bf(v); }

// ---------------- GEMM v3: Y = X @ W^T + bias ----------------------------
// 64xBN tile, 256 thr = 4 waves (2x2), wave tile 32x(BN/2).
// global_load_lds width-16 staging into LINEAR LDS (XOR slot swizzle on the
// per-lane GLOBAL source + matching swizzled ds_read). T4 counted-vmcnt
// pipeline: vmcnt(L) waits only for the PREVIOUS tile; never vmcnt(0) mid-loop.
template <typename XT, typename OT, bool RELU, int BN>
__global__ __launch_bounds__(256) void k_gemm3(
    const XT* __restrict__ X, const u16* __restrict__ W,
    const float* __restrict__ bias, OT* __restrict__ Y,
    int M, int N, int K)
{
    constexpr int WN  = BN / 2;          // wave col span
    constexpr int NFR = WN / 16;         // B frags per wave
    constexpr bool XF32 = (sizeof(XT) == 4);
    constexpr int L = (XF32 ? 2 : 1) + BN / 64;     // gload_lds per thread per stage
    constexpr int ASZ = 64 * 32 * (XF32 ? 2 : 1);   // u16 units
    constexpr int BSZ = BN * 32;
    __shared__ __align__(16) u16 As[2][ASZ];
    __shared__ __align__(16) u16 Bs[2][BSZ];

    const int tid = threadIdx.x;
    const int wave = tid >> 6, lane = tid & 63;
    const int wr = wave >> 1, wc = wave & 1;
    const int fr = lane & 15, fg = lane >> 4;
    const int bm = blockIdx.x * 64, bn = blockIdx.y * BN;

    f32x4 acc[2][NFR];
    #pragma unroll
    for (int m = 0; m < 2; ++m)
        #pragma unroll
        for (int n = 0; n < NFR; ++n) acc[m][n] = (f32x4){0.f, 0.f, 0.f, 0.f};

    auto stageA = [&](int buf, int kt) {
        if constexpr (!XF32) {
            int r = (wave << 4) + (lane >> 2);
            int grow = bm + r; if (grow > M - 1) grow = M - 1;
            int cs = (lane & 3) ^ ((lane >> 3) & 3);        // slot ^ ((r>>1)&3)
            gload16((const u16*)X + (size_t)grow * K + (kt << 5) + (cs << 3),
                    &As[buf][wave * 512]);
        } else {
            float* Af = (float*)As[buf];
            #pragma unroll
            for (int t = 0; t < 2; ++t) {
                int r = (t << 5) + (wave << 3) + (lane >> 3);
                int grow = bm + r; if (grow > M - 1) grow = M - 1;
                int cs = (lane & 7) ^ ((lane >> 3) & 7);    // slot ^ (r&7)
                gload16((const float*)X + (size_t)grow * K + (kt << 5) + (cs << 2),
                        &Af[((t << 5) + (wave << 3)) * 32]);
            }
        }
    };
    auto stageB = [&](int buf, int kt) {
        #pragma unroll
        for (int t = 0; t < BN / 64; ++t) {
            int r = (t << 6) + (wave << 4) + (lane >> 2);
            int cs = (lane & 3) ^ ((lane >> 3) & 3);
            gload16(W + (size_t)(bn + r) * K + (kt << 5) + (cs << 3),
                    &Bs[buf][((t << 6) + (wave << 4)) * 32]);
        }
    };

    stageA(0, 0); stageB(0, 0);

    const int nk = K >> 5;
    int cur = 0;
    for (int kt = 0; kt < nk; ++kt) {
        if (kt + 1 < nk) {
            stageA(cur ^ 1, kt + 1); stageB(cur ^ 1, kt + 1);
            waitvm<L>();             // previous tile landed; next stays in flight
        } else {
            waitvm<0>();
        }
        __builtin_amdgcn_s_barrier();

        bf16x8 af[2], bg[NFR];
        #pragma unroll
        for (int m = 0; m < 2; ++m) {
            int r = wr * 32 + m * 16 + fr;
            if constexpr (!XF32) {
                af[m] = *(const bf16x8*)&As[cur][r * 32 + ((fg ^ ((fr >> 1) & 3)) << 3)];
            } else {
                const float* Af = (const float*)As[cur];
                int s0 = (fg << 1) ^ (fr & 7);
                f32x4 x0 = *(const f32x4*)&Af[r * 32 + (s0 << 2)];
                f32x4 x1 = *(const f32x4*)&Af[r * 32 + ((s0 ^ 1) << 2)];
                #pragma unroll
                for (int j = 0; j < 4; ++j) {
                    af[m][j]     = (__bf16)x0[j];
                    af[m][4 + j] = (__bf16)x1[j];
                }
            }
        }
        #pragma unroll
        for (int n = 0; n < NFR; ++n) {
            int r = wc * WN + n * 16 + fr;
            bg[n] = *(const bf16x8*)&Bs[cur][r * 32 + ((fg ^ ((fr >> 1) & 3)) << 3)];
        }
        #pragma unroll
        for (int m = 0; m < 2; ++m)
            #pragma unroll
            for (int n = 0; n < NFR; ++n)
                acc[m][n] = mfma_bf16(af[m], bg[n], acc[m][n]);

        __builtin_amdgcn_s_barrier();
        cur ^= 1;
    }

    #pragma unroll
    for (int m = 0; m < 2; ++m) {
        #pragma unroll
        for (int i = 0; i < 4; ++i) {
            int grow = bm + wr * 32 + m * 16 + fg * 4 + i;
            if (grow >= M) continue;
            #pragma unroll
            for (int n = 0; n < NFR; ++n) {
                int gcol = bn + wc * WN + n * 16 + fr;
                float v = acc[m][n][i] + bias[gcol];
                if (RELU) v = fmaxf(v, 0.f);
                storey(Y + (size_t)grow * N + gcol, v);
            }
        }
    }
}

// ---------------- flash self-attention v3 (MFMA bf16, KVBLK=128) ----------------
// QK: fused [MQ,512] buffer (q = cols 0..255, k = cols 256..511), V: [MQ,256].
__global__ __launch_bounds__(256) void k_attn(
    const u16* __restrict__ QK, const u16* __restrict__ V, u16* __restrict__ O)
{
    __shared__ u16 Ks[128 * 40];       // [key][dh], stride 40
    __shared__ u16 Vt[32 * 136];       // [dh][kv-slot], stride 136 (permuted kv)
    const int b = blockIdx.z, h = blockIdx.y;
    const int q0 = blockIdx.x * 64;
    const int tid = threadIdx.x;
    const int wave = tid >> 6, lane = tid & 63;
    const int fr = lane & 15, fg = lane >> 4;
    constexpr float C2 = 0.25503486f;   // log2(e)/sqrt(32), folded into Q

    int qg = q0 + wave * 16 + fr; if (qg >= LQ_) qg = LQ_ - 1;
    bf16x8 qf;
    {
        bf16x8 qraw = *(const bf16x8*)&QK[((size_t)(b * LQ_ + qg)) * 512 + h * 32 + fg * 8];
        #pragma unroll
        for (int j = 0; j < 8; ++j) qf[j] = (__bf16)((float)qraw[j] * C2);
    }

    const bf16x8 ones = {(__bf16)1.f, (__bf16)1.f, (__bf16)1.f, (__bf16)1.f,
                         (__bf16)1.f, (__bf16)1.f, (__bf16)1.f, (__bf16)1.f};

    f32x4 o0 = (f32x4){0.f,0.f,0.f,0.f}, o1 = (f32x4){0.f,0.f,0.f,0.f};
    f32x4 lacc = (f32x4){0.f,0.f,0.f,0.f};

    const int kr = tid >> 1, kc = (tid & 1) * 16;   // K staging: row, col16
    const int vp = lane, vdh = wave * 8;            // V staging: kv-pair, dh block
    const int cp = ((vp >> 4) << 4) | (((vp >> 1) & 3) << 2) | (((vp >> 3) & 1) << 1) | (vp & 1);

    for (int kb0 = 0; kb0 < LQ_; kb0 += 128) {
        const bool tail = (kb0 + 128 > LQ_);
        __syncthreads();
        {
            int kg = kb0 + kr; if (kg >= LQ_) kg = LQ_ - 1;
            const u16* kp = &QK[((size_t)(b * LQ_ + kg)) * 512 + 256 + h * 32 + kc];
            *(bf16x8*)&Ks[kr * 40 + kc]     = *(const bf16x8*)kp;
            *(bf16x8*)&Ks[kr * 40 + kc + 8] = *(const bf16x8*)(kp + 8);
            int v0 = kb0 + 2 * vp, v1 = v0 + 1;
            if (v0 >= LQ_) v0 = LQ_ - 1;
            if (v1 >= LQ_) v1 = LQ_ - 1;
            union { bf16x8 v; u16 s[8]; } va, vb2;
            va.v  = *(const bf16x8*)&V[((size_t)(b * LQ_ + v0)) * 256 + h * 32 + vdh];
            vb2.v = *(const bf16x8*)&V[((size_t)(b * LQ_ + v1)) * 256 + h * 32 + vdh];
            #pragma unroll
            for (int j = 0; j < 8; ++j)
                *(u32*)&Vt[(vdh + j) * 136 + 2 * cp] = (u32)va.s[j] | ((u32)vb2.s[j] << 16);
        }
        __syncthreads();

        u32x4 pq[4];
        #pragma unroll
        for (int f = 0; f < 8; ++f) {
            bf16x8 ka = *(const bf16x8*)&Ks[(f * 16 + fr) * 40 + fg * 8];
            f32x4 s = mfma_bf16(ka, qf, (f32x4){0.f,0.f,0.f,0.f});
            if (tail) {
                #pragma unroll
                for (int i = 0; i < 4; ++i)
                    if (kb0 + f * 16 + fg * 4 + i >= LQ_) s[i] = -3e38f;
            }
            float p0 = EXP2(s[0]), p1 = EXP2(s[1]);
            float p2 = EXP2(s[2]), p3 = EXP2(s[3]);
            union { __bf16 h[2]; u32 w; } c0, c1;
            c0.h[0] = (__bf16)p0; c0.h[1] = (__bf16)p1;
            c1.h[0] = (__bf16)p2; c1.h[1] = (__bf16)p3;
            pq[f >> 1][(f & 1) * 2 + 0] = c0.w;
            pq[f >> 1][(f & 1) * 2 + 1] = c1.w;
        }

        #pragma unroll
        for (int ks = 0; ks < 4; ++ks) {
            bf16x8 pb  = __builtin_bit_cast(bf16x8, pq[ks]);
            bf16x8 va0 = *(const bf16x8*)&Vt[fr * 136 + ks * 32 + fg * 8];
            bf16x8 va1 = *(const bf16x8*)&Vt[(16 + fr) * 136 + ks * 32 + fg * 8];
            o0 = mfma_bf16(va0, pb, o0);
            o1 = mfma_bf16(va1, pb, o1);
            lacc = mfma_bf16(ones, pb, lacc);
        }
    }

    float inv = 1.f / lacc[0];
    int qout = q0 + wave * 16 + fr;
    if (qout < LQ_) {
        size_t base = ((size_t)(b * LQ_ + qout)) * 256 + h * 32;
        #pragma unroll
        for (int i = 0; i < 4; ++i) {
            O[base + fg * 4 + i]      = f2bf(o0[i] * inv);
            O[base + 16 + fg * 4 + i] = f2bf(o1[i] * inv);
        }
    }
}

// ---------------- residual + LayerNorm ----------------
__device__ __forceinline__ float ldf(const float* p) { return *p; }
__device__ __forceinline__ float ldf(const u16* p)   { return bf2f(*p); }

template <typename RT, typename OT>
__global__ __launch_bounds__(256) void k_resln(
    const u16* __restrict__ X, const RT* __restrict__ R,
    const float* __restrict__ g, const float* __restrict__ bb,
    OT* __restrict__ O)
{
    const int row = blockIdx.x;
    const int d = threadIdx.x;
    const size_t off = (size_t)row * D_ + d;
    float v = ldf(R + off) + bf2f(X[off]);
    __shared__ float r1[4], r2[4];
    int lane = d & 63, wid = d >> 6;
    float s = v;
    #pragma unroll
    for (int o_ = 32; o_ >= 1; o_ >>= 1) s += __shfl_xor(s, o_);
    if (lane == 0) r1[wid] = s;
    __syncthreads();
    float mean = (r1[0] + r1[1] + r1[2] + r1[3]) * (1.f / 256.f);
    float dv = v - mean;
    float sq = dv * dv;
    #pragma unroll
    for (int o_ = 32; o_ >= 1; o_ >>= 1) sq += __shfl_xor(sq, o_);
    if (lane == 0) r2[wid] = sq;
    __syncthreads();
    float var = (r2[0] + r2[1] + r2[2] + r2[3]) * (1.f / 256.f);
    storey(O + off, dv / sqrtf(var + 1e-5f) * g[d] + bb[d]);
}

// ---------------- deformable sampling (two-phase, LDS precompute) ----------------
// oaw: fused [MQ,384] f32 (offs = cols 0..255, aw = cols 256..383)
__global__ __launch_bounds__(256) void k_sample(
    const float* __restrict__ oaw,
    const u16* __restrict__ value, const float* __restrict__ refp,
    u16* __restrict__ acc_out)
{
    __shared__ u32 pts[2][128][8];   // [qsub][lp*8+h][0..3 off, 4..7 w]
    const int t = threadIdx.x;
    const int bq0 = blockIdx.x * 2;          // 2 queries, same batch (LQ even)
    const int b = bq0 / LQ_;

    constexpr int Hl[4] = {100, 50, 25, 13};
    constexpr int Wl[4] = {150, 75, 38, 19};
    constexpr int LS[4] = {0, 15000, 18750, 19700};

    // ---- phase 1 ----
    {
        const int qsub = t >> 7;
        const int pt = t & 127;
        const int h = pt >> 4, lp = pt & 15;
        const int l = lp >> 2, p = lp & 3;
        const int bq = bq0 + qsub;

        float2 oxy = *(const float2*)&oaw[(size_t)bq * 384 + h * 32 + l * 8 + p * 2];
        float av = oaw[(size_t)bq * 384 + 256 + h * 16 + lp];
        float mx = av;
        #pragma unroll
        for (int s = 1; s < 16; s <<= 1) mx = fmaxf(mx, __shfl_xor(mx, s));
        float e = __expf(av - mx);
        float sum = e;
        #pragma unroll
        for (int s = 1; s < 16; s <<= 1) sum += __shfl_xor(sum, s);
        float a = e / sum;

        float2 rxy = *(const float2*)&refp[(size_t)bq * 8 + l * 2];
        const float Wf = (float)Wl[l], Hf = (float)Hl[l];
        float x = (rxy.x + oxy.x / Wf) * Wf - 0.5f;
        float y = (rxy.y + oxy.y / Hf) * Hf - 0.5f;
        float x0f = floorf(x), y0f = floorf(y);
        int x0 = (int)x0f, y0 = (int)y0f;
        float wx1 = x - x0f, wy1 = y - y0f;
        float wx0 = 1.f - wx1, wy0 = 1.f - wy1;

        u32 ov[4]; float wv[4];
        #pragma unroll
        for (int c = 0; c < 4; ++c) {
            int cy = c >> 1, cx = c & 1;
            int yi = y0 + cy, xi = x0 + cx;
            bool valid = (yi >= 0) && (yi < Hl[l]) && (xi >= 0) && (xi < Wl[l]);
            ov[c] = valid ? (u32)((LS[l] + yi * Wl[l] + xi) * 256 + h * 32) : 0u;
            float w = (cy ? wy1 : wy0) * (cx ? wx1 : wx0) * a;
            wv[c] = valid ? w : 0.f;
        }
        u32* dst = pts[qsub][lp * 8 + h];
        *(uint4*)dst = make_uint4(ov[0], ov[1], ov[2], ov[3]);
        float4 wq = make_float4(wv[0], wv[1], wv[2], wv[3]);
        *(float4*)(dst + 4) = wq;
    }
    __syncthreads();

    // ---- phase 2 ----
    const int qsub = t >> 7;
    const int h = (t >> 4) & 7;
    const int dp = t & 15;                    // dh pair: dh = 2*dp, 2*dp+1
    const u16* vb = value + (size_t)b * LIN_ * 256 + 2 * dp;
    float a0 = 0.f, a1 = 0.f;
    #pragma unroll
    for (int i = 0; i < 16; ++i) {
        const u32* P = pts[qsub][i * 8 + h];
        uint4 o4 = *(const uint4*)P;
        float4 w4 = *(const float4*)(P + 4);
        u32 g;
        g = *(const u32*)&vb[o4.x]; a0 += w4.x * bf2f((u16)g); a1 += w4.x * bf2f((u16)(g >> 16));
        g = *(const u32*)&vb[o4.y]; a0 += w4.y * bf2f((u16)g); a1 += w4.y * bf2f((u16)(g >> 16));
        g = *(const u32*)&vb[o4.z]; a0 += w4.z * bf2f((u16)g); a1 += w4.z * bf2f((u16)(g >> 16));
        g = *(const u32*)&vb[o4.w]; a0 += w4.w * bf2f((u16)g); a1 += w4.w * bf2f((u16)(g >> 16));
    }
    const int bq = bq0 + qsub;
    u32 packed = (u32)f2bf(a0) | ((u32)f2bf(a1) << 16);
    *(u32*)&acc_out[(size_t)bq * 256 + h * 32 + 2 * dp] = packed;
}

// ---------------- launch ----------------
extern "C" void kernel_launch(void* const* d_in, const int* in_sizes, int n_in,
                              void* d_out, int out_size, void* d_ws, size_t ws_size,
                              hipStream_t stream)
{
    (void)in_sizes; (void)n_in; (void)out_size; (void)ws_size;
    const float* tgt   = (const float*)d_in[0];
    const float* qpos  = (const float*)d_in[1];
    const float* refp  = (const float*)d_in[2];
    const float* src   = (const float*)d_in[3];
    const float* qW    = (const float*)d_in[4];
    const float* qb    = (const float*)d_in[5];
    const float* kW    = (const float*)d_in[6];
    const float* kb    = (const float*)d_in[7];
    const float* vW    = (const float*)d_in[8];
    const float* vb    = (const float*)d_in[9];
    const float* oW    = (const float*)d_in[10];
    const float* ob    = (const float*)d_in[11];
    const float* a_q   = (const float*)d_in[12];
    const float* a_k   = (const float*)d_in[13];
    const float* a_v   = (const float*)d_in[14];
    const float* a_o   = (const float*)d_in[15];
    const float* val_W = (const float*)d_in[16];
    const float* val_b = (const float*)d_in[17];
    const float* a_val = (const float*)d_in[18];
    const float* off_W = (const float*)d_in[19];
    const float* off_b = (const float*)d_in[20];
    const float* aw_W  = (const float*)d_in[21];
    const float* aw_b  = (const float*)d_in[22];
    const float* out_W = (const float*)d_in[23];
    const float* out_b = (const float*)d_in[24];
    const float* a_out = (const float*)d_in[25];
    const float* W1    = (const float*)d_in[26];
    const float* b1    = (const float*)d_in[27];
    const float* a_w1  = (const float*)d_in[28];
    const float* W2    = (const float*)d_in[29];
    const float* b2    = (const float*)d_in[30];
    const float* a_w2  = (const float*)d_in[31];
    const float* ln1_g = (const float*)d_in[32];
    const float* ln1_b = (const float*)d_in[33];
    const float* ln2_g = (const float*)d_in[34];
    const float* ln2_b = (const float*)d_in[35];
    const float* ln3_g = (const float*)d_in[36];
    const float* ln3_b = (const float*)d_in[37];

    // ---- workspace layout ----
    // u16 weights: qk v o val out (6*65536) | W1 W2 (2*262144) | off aw
    u16* wbase = (u16*)d_ws;
    u16* wq_q  = wbase;                 // q at 0, k at 65536 (contiguous [512,256])
    u16* wq_v  = wbase + 131072;
    u16* wq_o  = wbase + 196608;
    u16* wq_vl = wbase + 262144;
    u16* wq_ot = wbase + 327680;
    u16* wq_1  = wbase + 393216;
    u16* wq_2  = wbase + 655360;
    u16* w_off = wbase + 917504;        // off (256 rows) + aw (128 rows) contiguous
    float* bfused = (float*)(wbase + 1015808);   // qkb[512] | oawb[384] (+pad)
    u16* bufA = (u16*)(bfused + 1024);
    u16* bufB = bufA + NELEM_;
    u16* bufC = bufB + NELEM_;          // bufC..bufD = fused qk [MQ,512]
    u16* bufD = bufC + NELEM_;
    u16* bufE = bufD + NELEM_;
    float* oaw = (float*)(bufE + NELEM_);        // [MQ,384] f32
    u16* valb  = (u16*)(oaw + (size_t)MQ_ * 384);// B*LIN*256 bf16 (reused as ffn1)

    const int TB = 256;
    const int MVAL = B_ * LIN_;
    const int GM = MQ_ / 64;                 // 225 (exact)
    const int GV = CDIV(MVAL, 64);           // 2494

    // ---- prep: all weight quant/cvt + fused biases, one dispatch ----
    k_prep<<<CDIV(1016704, TB), TB, 0, stream>>>(
        qW, kW, vW, oW, val_W, out_W, W1, W2, off_W, aw_W,
        a_q, a_k, a_v, a_o, a_val, a_out, a_w1, a_w2,
        qb, kb, off_b, aw_b, wbase, bfused);
    k_tgtprep<<<CDIV(NELEM_, TB), TB, 0, stream>>>(tgt, qpos, bufA, bufB, NELEM_);

    // ---- self-attention ----
    k_gemm3<u16, u16, false, 128><<<dim3(GM, 4), TB, 0, stream>>>(bufA, wq_q, bfused, bufC, MQ_, 512, 256);  // q||k
    k_gemm3<u16, u16, false, 128><<<dim3(GM, 2), TB, 0, stream>>>(bufB, wq_v, vb, bufE, MQ_, 256, 256);      // v
    k_attn<<<dim3(CDIV(LQ_,64), H_, B_), TB, 0, stream>>>(bufC, bufE, bufA);                                 // sa -> A
    k_gemm3<u16, u16, false, 128><<<dim3(GM, 2), TB, 0, stream>>>(bufA, wq_o, ob, bufD, MQ_, 256, 256);      // o -> D
    k_resln<float, u16><<<MQ_, TB, 0, stream>>>(bufD, tgt, ln2_g, ln2_b, bufC);                              // tgt2 -> C

    // ---- deformable cross-attention ----
    k_addcvt2<<<CDIV(NELEM_, TB), TB, 0, stream>>>(bufC, qpos, bufD, NELEM_);                                // query -> D
    k_gemm3<float, u16, false, 256><<<dim3(GV, 1), TB, 0, stream>>>(src, wq_vl, val_b, valb, MVAL, 256, 256);// value
    k_gemm3<u16, float, false, 128><<<dim3(GM, 3), TB, 0, stream>>>(bufD, w_off, bfused + 512, oaw, MQ_, 384, 256); // offs||aw
    k_sample<<<MQ_ / 2, TB, 0, stream>>>(oaw, valb, refp, bufE);                                             // acc -> E
    k_gemm3<u16, u16, false, 128><<<dim3(GM, 2), TB, 0, stream>>>(bufE, wq_ot, out_b, bufA, MQ_, 256, 256);  // ca -> A
    k_resln<u16, u16><<<MQ_, TB, 0, stream>>>(bufA, bufC, ln1_g, ln1_b, bufB);                               // tgt3 -> B

    // ---- FFN ----
    u16* ffn1 = valb;  // value dead after k_sample
    k_gemm3<u16, u16, true , 128><<<dim3(GM, 8), TB, 0, stream>>>(bufB, wq_1, b1, ffn1, MQ_, 1024, 256);
    k_gemm3<u16, u16, false, 128><<<dim3(GM, 2), TB, 0, stream>>>(ffn1, wq_2, b2, bufD, MQ_, 256, 1024);
    k_resln<u16, float><<<MQ_, TB, 0, stream>>>(bufD, bufB, ln3_g, ln3_b, (float*)d_out);
}